// Round 5
// baseline (146.141 us; speedup 1.0000x reference)
//
#include <hip/hip_runtime.h>

// Problem constants (from reference)
#define R_     4096
#define C_     16384
#define B_     32
#define NB_    (C_ / B_)     // 512
#define NC_    16
#define TOTAL  (R_ * C_)     // 67108864
#define TBITS  17
#define TSIZE  (1 << TBITS)  // 131072 hash slots (load factor 0.5)

// ---------------------------------------------------------------------------
// Main dequant kernel.
//   w = centroids[searchsorted(boundaries, x)] * s,  ties DOWN (side='left')
//
// Key numeric finding (rounds 1-4 bitwise triangulation): the reference
// quotient is NOT the correctly-rounded f32 division. XLA rewrites
// div(X, broadcast(s)) -> mul(X, broadcast(1/s)), so:
//       x_ref = fl32( e * fl32(1.0f / s) )        (two roundings)
// We reproduce exactly: correctly-rounded f32 reciprocal via guarded f64
// division + truncate (fast-math-proof), then a single f32 multiply.
// Boundaries (f32 add, *0.5 exact) and final w*s are single-rounding ops.
// ---------------------------------------------------------------------------
__global__ __launch_bounds__(256) void dequant_kernel(
    const float* __restrict__ master,
    const float* __restrict__ centroids,
    const float* __restrict__ scale,
    float* __restrict__ out)
{
    float c[NC_];
    float bnd[NC_ - 1];
#pragma unroll
    for (int j = 0; j < NC_; ++j) c[j] = centroids[j];
#pragma unroll
    for (int j = 0; j < NC_ - 1; ++j)
        bnd[j] = (c[j + 1] + c[j]) * 0.5f;   // f32 add (1 rounding), *0.5 exact

    const float4* m4 = reinterpret_cast<const float4*>(master);
    float4*       o4 = reinterpret_cast<float4*>(out);

    const int total4 = TOTAL / 4;                 // 16777216
    const int stride = gridDim.x * blockDim.x;

    for (int i4 = blockIdx.x * blockDim.x + threadIdx.x; i4 < total4; i4 += stride) {
        float4 v = m4[i4];
        // element block = (i4*4)/32 = i4>>3 ; scale is [R, NB] flat (= i/32)
        float s = scale[i4 >> 3];

        // Correctly-rounded f32 reciprocal r = fl32(1/s), fast-math-proof:
        // f64 divide (even a "fast" f64 div is ~1 ulp-f64 -> truncates to the
        // correct f32 a.s.), opaque asm blocks narrowing to f32 rcp.
        double rd = 1.0 / (double)s;
        asm volatile("" : "+v"(rd));
        float r = (float)rd;

        float e[4] = {v.x, v.y, v.z, v.w};
        float q[4];
#pragma unroll
        for (int k = 0; k < 4; ++k) {
            // x = fl32(e * r)  — matches XLA's mul-by-broadcast-reciprocal
            float x = (s != 0.0f) ? (e[k] * r) : 0.0f;   // safe_div
            // idx = #{bnd[j] < x}: ties DOWN (searchsorted side='left')
            float w = c[0];
#pragma unroll
            for (int j = 0; j < NC_ - 1; ++j)
                w = (x > bnd[j]) ? c[j + 1] : w;
            q[k] = w * s;
        }
        o4[i4] = make_float4(q[0], q[1], q[2], q[3]);
    }
}

// ---------------------------------------------------------------------------
// Sparse override with numpy last-write-wins semantics for duplicate indices.
// Hash table in workspace: keys[TSIZE] (init -1), vals[TSIZE] (init -1).
// Pass 1: insert key, atomicMax source-index. Pass 2: winner writes.
// ---------------------------------------------------------------------------
__global__ void hash_insert(const int* __restrict__ sidx, int ns,
                            int* __restrict__ keys, int* __restrict__ vals)
{
    int i = blockIdx.x * blockDim.x + threadIdx.x;
    if (i >= ns) return;
    int key = sidx[i];
    unsigned h = ((unsigned)key * 2654435761u) >> (32 - TBITS);
    for (;;) {
        int prev = atomicCAS(&keys[h], -1, key);
        if (prev == -1 || prev == key) {
            atomicMax(&vals[h], i);   // last occurrence (max i) wins
            return;
        }
        h = (h + 1) & (TSIZE - 1);
    }
}

__global__ void hash_scatter(const int* __restrict__ sidx,
                             const float* __restrict__ sw, int ns,
                             const int* __restrict__ keys,
                             const int* __restrict__ vals,
                             float* __restrict__ out)
{
    int i = blockIdx.x * blockDim.x + threadIdx.x;
    if (i >= ns) return;
    int key = sidx[i];
    unsigned h = ((unsigned)key * 2654435761u) >> (32 - TBITS);
    for (;;) {
        if (keys[h] == key) {
            if (vals[h] == i) out[key] = sw[i];
            return;
        }
        h = (h + 1) & (TSIZE - 1);
    }
}

// Fallback if workspace is unexpectedly tiny: sequential = last-write-wins.
__global__ void serial_scatter(const int* __restrict__ sidx,
                               const float* __restrict__ sw, int ns,
                               float* __restrict__ out)
{
    if (blockIdx.x == 0 && threadIdx.x == 0) {
        for (int i = 0; i < ns; ++i) out[sidx[i]] = sw[i];
    }
}

extern "C" void kernel_launch(void* const* d_in, const int* in_sizes, int n_in,
                              void* d_out, int out_size, void* d_ws, size_t ws_size,
                              hipStream_t stream)
{
    const float* master    = (const float*)d_in[0];
    const float* centroids = (const float*)d_in[1];
    const float* scale     = (const float*)d_in[2];
    const float* sweight   = (const float*)d_in[3];
    const int*   sidx      = (const int*)d_in[4];
    float*       out       = (float*)d_out;
    const int    ns        = in_sizes[4];

    // 2048 blocks x 256 threads = 8 blocks/CU; 32 float4/thread grid-stride
    dequant_kernel<<<2048, 256, 0, stream>>>(master, centroids, scale, out);

    const size_t table_bytes = (size_t)TSIZE * 2 * sizeof(int);
    if (ws_size >= table_bytes) {
        hipMemsetAsync(d_ws, 0xFF, table_bytes, stream);  // keys = vals = -1
        int* keys = (int*)d_ws;
        int* vals = keys + TSIZE;
        int blocks = (ns + 255) / 256;
        hash_insert<<<blocks, 256, 0, stream>>>(sidx, ns, keys, vals);
        hash_scatter<<<blocks, 256, 0, stream>>>(sidx, sweight, ns, keys, vals, out);
    } else {
        serial_scatter<<<1, 1, 0, stream>>>(sidx, sweight, ns, out);
    }
}

// Round 6
// 133.614 us; speedup vs baseline: 1.0938x; 1.0938x over previous
//
#include <hip/hip_runtime.h>

// Problem constants (from reference)
#define R_     4096
#define C_     16384
#define B_     32
#define NB_    (C_ / B_)     // 512
#define NC_    16
#define TOTAL  (R_ * C_)     // 67108864
#define TBITS  17
#define TSIZE  (1 << TBITS)  // 131072 hash slots (load factor 0.5)

#define GRID_  2048
#define BLK_   256
#define ITERS_ (TOTAL / 4 / (GRID_ * BLK_))   // 32
static_assert(GRID_ * BLK_ * ITERS_ * 4 == TOTAL, "grid must tile exactly");

typedef float f32x4 __attribute__((ext_vector_type(4)));

// ---------------------------------------------------------------------------
// Main dequant kernel.
//   w = centroids[searchsorted(boundaries, x)] * s,  ties DOWN (side='left')
//   x = fl32( e * fl32(1/s) )   <- matches XLA's div->mul(1/s) rewrite
// VERIFIED BITWISE in round 5 (absmax 0.0). Numerics below are frozen:
//  - r = fl32(1/s) via guarded f64 divide (fast-math-proof, correctly rounded)
//  - boundaries (c[j+1]+c[j])*0.5f in f32
//  - strict '>' select chain (ties down), final w*s single f32 mul
// This round: non-temporal streaming loads/stores (no reuse; 536 MB through
// 32 MB L2 is pure thrash) + fixed trip-count loop for compiler pipelining.
// ---------------------------------------------------------------------------
__global__ __launch_bounds__(BLK_) void dequant_kernel(
    const float* __restrict__ master,
    const float* __restrict__ centroids,
    const float* __restrict__ scale,
    float* __restrict__ out)
{
    float c[NC_];
    float bnd[NC_ - 1];
#pragma unroll
    for (int j = 0; j < NC_; ++j) c[j] = centroids[j];
#pragma unroll
    for (int j = 0; j < NC_ - 1; ++j)
        bnd[j] = (c[j + 1] + c[j]) * 0.5f;   // f32 add (1 rounding), *0.5 exact

    const f32x4* m4 = reinterpret_cast<const f32x4*>(master);
    f32x4*       o4 = reinterpret_cast<f32x4*>(out);

    const int tid = blockIdx.x * BLK_ + threadIdx.x;

#pragma unroll 2
    for (int k = 0; k < ITERS_; ++k) {
        const int i4 = tid + k * (GRID_ * BLK_);
        f32x4 v = __builtin_nontemporal_load(m4 + i4);
        // element block = (i4*4)/32 = i4>>3 ; scale is [R, NB] flat
        float s = scale[i4 >> 3];

        // Correctly-rounded f32 reciprocal r = fl32(1/s), fast-math-proof.
        double rd = 1.0 / (double)s;
        asm volatile("" : "+v"(rd));
        float r = (float)rd;

        f32x4 q;
#pragma unroll
        for (int kk = 0; kk < 4; ++kk) {
            float x = (s != 0.0f) ? (v[kk] * r) : 0.0f;   // safe_div
            // idx = #{bnd[j] < x}: ties DOWN (searchsorted side='left')
            float w = c[0];
#pragma unroll
            for (int j = 0; j < NC_ - 1; ++j)
                w = (x > bnd[j]) ? c[j + 1] : w;
            q[kk] = w * s;
        }
        __builtin_nontemporal_store(q, o4 + i4);
    }
}

// ---------------------------------------------------------------------------
// Sparse override with numpy last-write-wins semantics for duplicate indices.
// Hash table in workspace: keys[TSIZE] (init -1), vals[TSIZE] (init -1).
// Pass 1: insert key, atomicMax source-index. Pass 2: winner writes.
// ---------------------------------------------------------------------------
__global__ void hash_insert(const int* __restrict__ sidx, int ns,
                            int* __restrict__ keys, int* __restrict__ vals)
{
    int i = blockIdx.x * blockDim.x + threadIdx.x;
    if (i >= ns) return;
    int key = sidx[i];
    unsigned h = ((unsigned)key * 2654435761u) >> (32 - TBITS);
    for (;;) {
        int prev = atomicCAS(&keys[h], -1, key);
        if (prev == -1 || prev == key) {
            atomicMax(&vals[h], i);   // last occurrence (max i) wins
            return;
        }
        h = (h + 1) & (TSIZE - 1);
    }
}

__global__ void hash_scatter(const int* __restrict__ sidx,
                             const float* __restrict__ sw, int ns,
                             const int* __restrict__ keys,
                             const int* __restrict__ vals,
                             float* __restrict__ out)
{
    int i = blockIdx.x * blockDim.x + threadIdx.x;
    if (i >= ns) return;
    int key = sidx[i];
    unsigned h = ((unsigned)key * 2654435761u) >> (32 - TBITS);
    for (;;) {
        if (keys[h] == key) {
            if (vals[h] == i) out[key] = sw[i];
            return;
        }
        h = (h + 1) & (TSIZE - 1);
    }
}

// Fallback if workspace is unexpectedly tiny: sequential = last-write-wins.
__global__ void serial_scatter(const int* __restrict__ sidx,
                               const float* __restrict__ sw, int ns,
                               float* __restrict__ out)
{
    if (blockIdx.x == 0 && threadIdx.x == 0) {
        for (int i = 0; i < ns; ++i) out[sidx[i]] = sw[i];
    }
}

extern "C" void kernel_launch(void* const* d_in, const int* in_sizes, int n_in,
                              void* d_out, int out_size, void* d_ws, size_t ws_size,
                              hipStream_t stream)
{
    const float* master    = (const float*)d_in[0];
    const float* centroids = (const float*)d_in[1];
    const float* scale     = (const float*)d_in[2];
    const float* sweight   = (const float*)d_in[3];
    const int*   sidx      = (const int*)d_in[4];
    float*       out       = (float*)d_out;
    const int    ns        = in_sizes[4];

    dequant_kernel<<<GRID_, BLK_, 0, stream>>>(master, centroids, scale, out);

    const size_t table_bytes = (size_t)TSIZE * 2 * sizeof(int);
    if (ws_size >= table_bytes) {
        hipMemsetAsync(d_ws, 0xFF, table_bytes, stream);  // keys = vals = -1
        int* keys = (int*)d_ws;
        int* vals = keys + TSIZE;
        int blocks = (ns + 255) / 256;
        hash_insert<<<blocks, 256, 0, stream>>>(sidx, ns, keys, vals);
        hash_scatter<<<blocks, 256, 0, stream>>>(sidx, sweight, ns, keys, vals, out);
    } else {
        serial_scatter<<<1, 1, 0, stream>>>(sidx, sweight, ns, out);
    }
}